// Round 7
// baseline (180.521 us; speedup 1.0000x reference)
//
#include <hip/hip_runtime.h>
#include <hip/hip_bf16.h>

#define B_ 2
#define C_ 256
#define H_ 64
#define W_ 64
#define N_ 4096  // H_*W_

typedef short bf16x8 __attribute__((ext_vector_type(8)));
typedef _Float16 f16x8 __attribute__((ext_vector_type(8)));
typedef float f32x4 __attribute__((ext_vector_type(4)));

// float -> bf16 (round to nearest even), finite inputs
static __device__ __forceinline__ unsigned short f2bf(float f) {
    union { float f; unsigned u; } uf; uf.f = f;
    unsigned r = uf.u + 0x7fffu + ((uf.u >> 16) & 1u);
    return (unsigned short)(r >> 16);
}
// float -> fp16 bits
static __device__ __forceinline__ unsigned short f2h_u(float f) {
    union { _Float16 h; unsigned short u; } c; c.h = (_Float16)f; return c.u;
}

// async global->LDS, 16B per lane. LDS dest must be wave-uniform base + lane*16.
static __device__ __forceinline__ void gload16(const void* g, void* l) {
    __builtin_amdgcn_global_load_lds(
        (const __attribute__((address_space(1))) unsigned int*)g,
        (__attribute__((address_space(3))) unsigned int*)l, 16, 0, 0);
}

// ---------------------------------------------------------------------------
// Prep: [B][C][N] f32 -> [B][N][C] fp16, both inputs in one launch.
// ---------------------------------------------------------------------------
__global__ __launch_bounds__(256) void cvt_x_k(const float* __restrict__ x,
                                               const float* __restrict__ ref_x,
                                               unsigned short* __restrict__ xtx,
                                               unsigned short* __restrict__ xtr)
{
    __shared__ unsigned short t[64][72];
    const int pt = blockIdx.x, ct = blockIdx.y;
    const int which = blockIdx.z >> 1, b = blockIdx.z & 1;
    const float* in = which ? ref_x : x;
    unsigned short* out = which ? xtr : xtx;
    const int a = threadIdx.x & 63, r = threadIdx.x >> 6;
    #pragma unroll
    for (int i = 0; i < 16; ++i) {
        int c = i * 4 + r;
        t[c][a] = f2h_u(in[((size_t)(b * C_ + ct * 64 + c) << 12) + pt * 64 + a]);
    }
    __syncthreads();
    #pragma unroll
    for (int i = 0; i < 16; ++i) {
        int p = i * 4 + r;
        out[((size_t)(b * N_ + pt * 64 + p) << 8) + ct * 64 + a] = t[a][p];
    }
}

// Prep: both weights [O][I][3][3] f32 -> [tap][O][I] fp16 in one launch
__global__ __launch_bounds__(256) void cvt_w_k(const float* __restrict__ w1,
                                               const float* __restrict__ w2,
                                               unsigned short* __restrict__ wh1,
                                               unsigned short* __restrict__ wh2)
{
    int g = blockIdx.x;
    const float* w = (g < 2304) ? w1 : w2;
    unsigned short* wh = (g < 2304) ? wh1 : wh2;
    int i = (g % 2304) * 256 + threadIdx.x;         // < 9*256*256 exactly
    int ci = i & 255, co = (i >> 8) & 255, tap = i >> 16;
    wh[i] = f2h_u(w[((size_t)(co * 256 + ci)) * 9 + tap]);
}

// ---------------------------------------------------------------------------
// Implicit-GEMM 3x3 conv + bias + relu, MFMA 16x16x32 fp16.
// KEY: weights are NOT staged in LDS — w-fragments load straight from global
// (L2-resident, 1.2MB) into regs, reused across 4 pos-frags. LDS holds only
// the x-window (4 rows x 66 cols x 32k, col-xor chunk swizzle, 16.9KB).
// Block: 128 thr = 2 waves; wave w = plane row r0+w, 64co x 64pos (4x4 frags).
// Grid 32(pt) x 4(cot) x 6(cid,b) = 768 blocks = 3 blocks/CU.
// ---------------------------------------------------------------------------
__global__ __launch_bounds__(128) void conv_mfma_k(
    const unsigned short* __restrict__ xtx, const unsigned short* __restrict__ xtr,
    const unsigned short* __restrict__ w1h, const unsigned short* __restrict__ w2h,
    const float* __restrict__ b1, const float* __restrict__ b2,
    unsigned short* __restrict__ f1x, unsigned short* __restrict__ f1r,
    unsigned short* __restrict__ f2)
{
    __shared__ unsigned short Bs[4 * 66 * 32];   // (row*66+col)*32 + swzchunk*8
    const int tid = threadIdx.x;
    const int pt  = blockIdx.x;   // 0..31 : plane rows pt*2, pt*2+1
    const int cot = blockIdx.y;   // 0..3
    const int cid = blockIdx.z >> 1;
    const int b   = blockIdx.z & 1;

    const unsigned short* xt = (cid == 1) ? xtr : xtx;
    const unsigned short* wt = (cid == 2) ? w2h : w1h;
    const float* bias = (cid == 2) ? b2 : b1;
    unsigned short* out = (cid == 0) ? f1x : (cid == 1) ? f1r : f2;
    const int trans = (cid != 2);

    const int lane = tid & 63, wid = tid >> 6;   // wid 0..1
    const int rl = lane & 15, q = lane >> 4;
    const int r0 = pt * 2;

    f32x4 acc[4][4];   // [co-frag][pos-frag]
    #pragma unroll
    for (int cf = 0; cf < 4; ++cf)
        #pragma unroll
        for (int pf = 0; pf < 4; ++pf)
            #pragma unroll
            for (int e = 0; e < 4; ++e) acc[cf][pf][e] = 0.f;

    for (int k0 = 0; k0 < C_; k0 += 32) {
        // stage x-window: 4 rows x 66 cols x 4 chunks = 1056 16B chunks
        #pragma unroll
        for (int j = 0; j < 9; ++j) {
            int it = tid + j * 128;
            if (it < 1056) {
                int col = it >> 4, sub = it & 15;
                int row = sub >> 2, qb = sub & 3;
                int h = r0 + row - 1, c = col - 1;
                float4 v; v.x = 0.f; v.y = 0.f; v.z = 0.f; v.w = 0.f;
                if (h >= 0 && h < 64 && c >= 0 && c < 64)
                    v = *(const float4*)(xt + ((size_t)(b * N_ + h * 64 + c) << 8) + k0 + qb * 8);
                int chunk = qb ^ ((col >> 1) & 3);
                *(float4*)&Bs[(row * 66 + col) * 32 + chunk * 8] = v;
            }
        }
        __syncthreads();

        #pragma unroll
        for (int tap = 0; tap < 9; ++tap) {
            const int kh = tap / 3, kw = tap % 3;
            // weight fragments straight from global (L2): 4 co-frags
            f16x8 w[4];
            #pragma unroll
            for (int cf = 0; cf < 4; ++cf)
                w[cf] = *(const f16x8*)&wt[((size_t)(tap * C_ + cot * 64 + cf * 16 + rl) << 8)
                                           + k0 + q * 8];
            const int rowB = (wid + kh) * 66;
            const int swz = ((rl + kw) >> 1) & 3;
            #pragma unroll
            for (int pf = 0; pf < 4; ++pf) {
                const int colB = pf * 16 + rl + kw;
                f16x8 xv = *(const f16x8*)&Bs[(rowB + colB) * 32 + (q ^ swz) * 8];
                #pragma unroll
                for (int cf = 0; cf < 4; ++cf)
                    acc[cf][pf] = __builtin_amdgcn_mfma_f32_16x16x32_f16(w[cf], xv, acc[cf][pf], 0, 0, 0);
            }
        }
        __syncthreads();
    }

    // epilogue: C/D layout col(pos)=lane&15, row(co)=(lane>>4)*4+reg
    const int prow = r0 + wid;
    #pragma unroll
    for (int cf = 0; cf < 4; ++cf) {
        const int co0 = cot * 64 + cf * 16 + q * 4;
        float bs[4];
        #pragma unroll
        for (int rr = 0; rr < 4; ++rr) bs[rr] = bias[co0 + rr];
        #pragma unroll
        for (int pf = 0; pf < 4; ++pf) {
            const int pos = prow * 64 + pf * 16 + rl;
            if (trans) {
                unsigned short pk[4];
                #pragma unroll
                for (int rr = 0; rr < 4; ++rr)
                    pk[rr] = f2bf(fmaxf(acc[cf][pf][rr] + bs[rr], 0.f));
                uint2 u;
                u.x = (unsigned)pk[0] | ((unsigned)pk[1] << 16);
                u.y = (unsigned)pk[2] | ((unsigned)pk[3] << 16);
                *(uint2*)&out[((size_t)(b * N_ + pos) << 8) + co0] = u;
            } else {
                #pragma unroll
                for (int rr = 0; rr < 4; ++rr)
                    out[((size_t)(b * C_ + co0 + rr) << 12) + pos] =
                        f2bf(fmaxf(acc[cf][pf][rr] + bs[rr], 0.f));
            }
        }
    }
}

// ---------------------------------------------------------------------------
// GEMM1 (m97 structure + chunk swizzle): corrT[b][m][n] = sum_c f1x.f1r
// 128x128 tile, 4 waves (2x2, each 64x64 = 4x4 frags), global_load_lds with
// pre-swizzled SOURCE chunk (dest lane-linear), swizzled read chunk.
// ---------------------------------------------------------------------------
__global__ __launch_bounds__(256) void gemm_corr_k(
    const unsigned short* __restrict__ f1x, const unsigned short* __restrict__ f1r,
    float* __restrict__ corr)
{
    __shared__ alignas(16) unsigned short As[128 * 32];
    __shared__ alignas(16) unsigned short Bs[128 * 32];
    const int tid = threadIdx.x;
    const int tn = blockIdx.x, tm = blockIdx.y, b = blockIdx.z;

    const unsigned short* Ab = f1x + ((size_t)b * N_ + (size_t)tm * 128) * C_;
    const unsigned short* Bb = f1r + ((size_t)b * N_ + (size_t)tn * 128) * C_;

    const int wid = tid >> 6, lane = tid & 63;
    const int wr = wid >> 1, wc = wid & 1;
    const int rl = lane & 15, q = lane >> 4;
    const int srow = wid * 32 + (lane >> 2), sq = lane & 3;
    const int logq = sq ^ ((lane >> 3) & 3);          // pre-swizzled source chunk
    const int rswz = (rl >> 1) & 3;                   // read-side chunk xor

    f32x4 acc[4][4];
    #pragma unroll
    for (int mi = 0; mi < 4; ++mi)
        #pragma unroll
        for (int ni = 0; ni < 4; ++ni)
            #pragma unroll
            for (int e = 0; e < 4; ++e) acc[mi][ni][e] = 0.f;

    for (int k0 = 0; k0 < C_; k0 += 32) {
        gload16(&Ab[(size_t)srow * C_ + k0 + logq * 8],        &As[srow * 32 + sq * 8]);
        gload16(&Ab[(size_t)(srow + 16) * C_ + k0 + logq * 8], &As[(srow + 16) * 32 + sq * 8]);
        gload16(&Bb[(size_t)srow * C_ + k0 + logq * 8],        &Bs[srow * 32 + sq * 8]);
        gload16(&Bb[(size_t)(srow + 16) * C_ + k0 + logq * 8], &Bs[(srow + 16) * 32 + sq * 8]);
        __syncthreads();
        bf16x8 a[4], bb[4];
        #pragma unroll
        for (int mi = 0; mi < 4; ++mi)
            a[mi] = *(const bf16x8*)&As[(wr * 64 + mi * 16 + rl) * 32 + (q ^ rswz) * 8];
        #pragma unroll
        for (int ni = 0; ni < 4; ++ni)
            bb[ni] = *(const bf16x8*)&Bs[(wc * 64 + ni * 16 + rl) * 32 + (q ^ rswz) * 8];
        #pragma unroll
        for (int mi = 0; mi < 4; ++mi)
            #pragma unroll
            for (int ni = 0; ni < 4; ++ni)
                acc[mi][ni] = __builtin_amdgcn_mfma_f32_16x16x32_bf16(a[mi], bb[ni], acc[mi][ni], 0, 0, 0);
        __syncthreads();
    }

    #pragma unroll
    for (int mi = 0; mi < 4; ++mi)
        #pragma unroll
        for (int ni = 0; ni < 4; ++ni)
            #pragma unroll
            for (int rr = 0; rr < 4; ++rr) {
                int m = tm * 128 + wr * 64 + mi * 16 + q * 4 + rr;
                int n = tn * 128 + wc * 64 + ni * 16 + rl;
                corr[((size_t)b * N_ + m) * N_ + n] = acc[mi][ni][rr];
            }
}

// ---------------------------------------------------------------------------
// Row softmax over corrT rows; reads fp32, writes bf16 packed into the
// FRONT half of the same row (in-place, block owns its row).
// ---------------------------------------------------------------------------
__global__ __launch_bounds__(256) void softmax_rows_k(float* __restrict__ corr)
{
    __shared__ float red[4];
    const int m = blockIdx.x, b = blockIdx.y;
    float* row = corr + ((size_t)b * N_ + m) * N_;
    float4* row4 = (float4*)row;
    const int tid = threadIdx.x;
    const int wid = tid >> 6, lane = tid & 63;

    float4 v[4];
    float mx = -3.0e38f;
    #pragma unroll
    for (int j = 0; j < 4; ++j) {
        v[j] = row4[tid + j * 256];
        mx = fmaxf(mx, fmaxf(fmaxf(v[j].x, v[j].y), fmaxf(v[j].z, v[j].w)));
    }
    #pragma unroll
    for (int off = 32; off; off >>= 1) mx = fmaxf(mx, __shfl_xor(mx, off));
    if (lane == 0) red[wid] = mx;
    __syncthreads();
    mx = fmaxf(fmaxf(red[0], red[1]), fmaxf(red[2], red[3]));
    __syncthreads();

    float s = 0.f;
    #pragma unroll
    for (int j = 0; j < 4; ++j) {
        v[j].x = __expf(v[j].x - mx);
        v[j].y = __expf(v[j].y - mx);
        v[j].z = __expf(v[j].z - mx);
        v[j].w = __expf(v[j].w - mx);
        s += v[j].x + v[j].y + v[j].z + v[j].w;
    }
    #pragma unroll
    for (int off = 32; off; off >>= 1) s += __shfl_xor(s, off);
    if (lane == 0) red[wid] = s;
    __syncthreads();
    s = red[0] + red[1] + red[2] + red[3];
    const float inv = 1.f / s;

    unsigned short* rb = (unsigned short*)row;
    #pragma unroll
    for (int j = 0; j < 4; ++j) {
        uint2 u;
        u.x = (unsigned)f2bf(v[j].x * inv) | ((unsigned)f2bf(v[j].y * inv) << 16);
        u.y = (unsigned)f2bf(v[j].z * inv) | ((unsigned)f2bf(v[j].w * inv) << 16);
        *(uint2*)&rb[4 * (tid + j * 256)] = u;
    }
}

// ---------------------------------------------------------------------------
// GEMM2 split-K=4 + chunk swizzle: partial[s][b][c][m] over n-range.
// Tile 128c x 128m, 8 waves (2c x 4m). blockIdx.y = tc*4 + s. Grid 512.
// P read as bf16 (front half of fp32 corr rows, row stride 8192 ushorts).
// Partials live in the DEAD BACK HALVES of corr rows.
// ---------------------------------------------------------------------------
__global__ __launch_bounds__(512) void gemm_out_k(
    const unsigned short* __restrict__ f2, float* __restrict__ corr)
{
    __shared__ alignas(16) unsigned short As[128 * 32];
    __shared__ alignas(16) unsigned short Bs[128 * 32];
    const int tid = threadIdx.x;
    const int tm = blockIdx.x;                 // 0..31
    const int tc = blockIdx.y >> 2;            // 0..1
    const int s  = blockIdx.y & 3;             // split 0..3
    const int b  = blockIdx.z;

    const unsigned short* Ab = f2 + ((size_t)b * C_ + (size_t)tc * 128) * N_;
    const unsigned short* Bb = (const unsigned short*)corr
                             + ((size_t)b * N_ + (size_t)tm * 128) * 8192;

    const int wid = tid >> 6, lane = tid & 63;
    const int wc = wid >> 2, wm = wid & 3;
    const int rl = lane & 15, q = lane >> 4;
    const int srow = wid * 16 + (lane >> 2), sq = lane & 3;
    const int logq = sq ^ ((lane >> 3) & 3);
    const int rswz = (rl >> 1) & 3;
    const int nbase = s * 1024;

    f32x4 acc[4][2];
    #pragma unroll
    for (int mi = 0; mi < 4; ++mi)
        #pragma unroll
        for (int ni = 0; ni < 2; ++ni)
            #pragma unroll
            for (int e = 0; e < 4; ++e) acc[mi][ni][e] = 0.f;

    for (int kk = 0; kk < 32; ++kk) {
        const int k0 = nbase + kk * 32;
        gload16(&Ab[(size_t)srow * N_ + k0 + logq * 8],   &As[srow * 32 + sq * 8]);
        gload16(&Bb[(size_t)srow * 8192 + k0 + logq * 8], &Bs[srow * 32 + sq * 8]);
        __syncthreads();
        bf16x8 a[4], bb[2];
        #pragma unroll
        for (int mi = 0; mi < 4; ++mi)
            a[mi] = *(const bf16x8*)&As[(wc * 64 + mi * 16 + rl) * 32 + (q ^ rswz) * 8];
        #pragma unroll
        for (int ni = 0; ni < 2; ++ni)
            bb[ni] = *(const bf16x8*)&Bs[(wm * 32 + ni * 16 + rl) * 32 + (q ^ rswz) * 8];
        #pragma unroll
        for (int mi = 0; mi < 4; ++mi)
            #pragma unroll
            for (int ni = 0; ni < 2; ++ni)
                acc[mi][ni] = __builtin_amdgcn_mfma_f32_16x16x32_bf16(a[mi], bb[ni], acc[mi][ni], 0, 0, 0);
        __syncthreads();
    }

    #pragma unroll
    for (int mi = 0; mi < 4; ++mi)
        #pragma unroll
        for (int ni = 0; ni < 2; ++ni)
            #pragma unroll
            for (int rr = 0; rr < 4; ++rr) {
                int c = tc * 128 + wc * 64 + mi * 16 + q * 4 + rr;
                int m = tm * 128 + wm * 32 + ni * 16 + rl;
                size_t e = (((size_t)(s * 2 + b) * C_ + c) << 12) + m;
                corr[(e >> 11) * 4096 + 2048 + (e & 2047)] = acc[mi][ni][rr];
            }
}

// out = gamma*(p0+p1+p2+p3) + x ; partials read back from corr back-halves
__global__ __launch_bounds__(256) void reduce_k(
    const float* __restrict__ corr, const float* __restrict__ x,
    const float* __restrict__ gamma, float* __restrict__ out)
{
    const float g = gamma[0];
    size_t i = (size_t)blockIdx.x * 256 + threadIdx.x;   // float4 index
    size_t idx = i << 2;                                  // flat f32 index (b,c,m)
    float4 sum; sum.x = 0.f; sum.y = 0.f; sum.z = 0.f; sum.w = 0.f;
    #pragma unroll
    for (int sp = 0; sp < 4; ++sp) {
        size_t e = (size_t)sp * 2097152 + idx;
        float4 v = *(const float4*)&corr[(e >> 11) * 4096 + 2048 + (e & 2047)];
        sum.x += v.x; sum.y += v.y; sum.z += v.z; sum.w += v.w;
    }
    float4 xv = ((const float4*)x)[i];
    float4 o;
    o.x = sum.x * g + xv.x;
    o.y = sum.y * g + xv.y;
    o.z = sum.z * g + xv.z;
    o.w = sum.w * g + xv.w;
    ((float4*)out)[i] = o;
}

extern "C" void kernel_launch(void* const* d_in, const int* in_sizes, int n_in,
                              void* d_out, int out_size, void* d_ws, size_t ws_size,
                              hipStream_t stream) {
    const float* x     = (const float*)d_in[0];
    const float* ref_x = (const float*)d_in[1];
    const float* w1    = (const float*)d_in[2];
    const float* b1    = (const float*)d_in[3];
    const float* w2    = (const float*)d_in[4];
    const float* b2    = (const float*)d_in[5];
    const float* gamma = (const float*)d_in[6];
    float* out = (float*)d_out;

    char* ws = (char*)d_ws;
    size_t off = 0;
    auto nxt = [&](size_t bytes) {
        char* p = ws + off;
        off += (bytes + 255) & ~(size_t)255;
        return p;
    };
    unsigned short* f1x = (unsigned short*)nxt((size_t)B_ * N_ * C_ * 2);  // bf16 [b][m][c]
    unsigned short* f1r = (unsigned short*)nxt((size_t)B_ * N_ * C_ * 2);  // bf16 [b][n][c]
    unsigned short* f2  = (unsigned short*)nxt((size_t)B_ * N_ * C_ * 2);  // bf16 [b][c][n]
    unsigned short* xtx = (unsigned short*)nxt((size_t)B_ * N_ * C_ * 2);  // fp16 [b][p][c]
    unsigned short* xtr = (unsigned short*)nxt((size_t)B_ * N_ * C_ * 2);  // fp16 [b][p][c]
    unsigned short* w1h = (unsigned short*)nxt((size_t)9 * C_ * C_ * 2);   // fp16 [tap][o][i]
    unsigned short* w2h = (unsigned short*)nxt((size_t)9 * C_ * C_ * 2);   // fp16 [tap][o][i]
    float* corr = (float*)nxt((size_t)B_ * N_ * N_ * 4);                   // fp32 corrT [b][m][n]

    cvt_x_k<<<dim3(64, 4, 4), 256, 0, stream>>>(x, ref_x, xtx, xtr);
    cvt_w_k<<<4608, 256, 0, stream>>>(w1, w2, w1h, w2h);

    conv_mfma_k<<<dim3(32, 4, 6), 128, 0, stream>>>(xtx, xtr, w1h, w2h, b1, b2,
                                                    f1x, f1r, f2);

    gemm_corr_k<<<dim3(32, 32, B_), 256, 0, stream>>>(f1x, f1r, corr);
    softmax_rows_k<<<dim3(N_, B_), 256, 0, stream>>>(corr);
    gemm_out_k<<<dim3(32, 8, B_), 512, 0, stream>>>(f2, corr);
    reduce_k<<<2048, 256, 0, stream>>>(corr, x, gamma, out);
}

// Round 8
// 176.388 us; speedup vs baseline: 1.0234x; 1.0234x over previous
//
#include <hip/hip_runtime.h>
#include <hip/hip_bf16.h>

#define B_ 2
#define C_ 256
#define H_ 64
#define W_ 64
#define N_ 4096  // H_*W_

typedef short bf16x8 __attribute__((ext_vector_type(8)));
typedef _Float16 f16x8 __attribute__((ext_vector_type(8)));
typedef float f32x4 __attribute__((ext_vector_type(4)));

// float -> bf16 (round to nearest even), finite inputs
static __device__ __forceinline__ unsigned short f2bf(float f) {
    union { float f; unsigned u; } uf; uf.f = f;
    unsigned r = uf.u + 0x7fffu + ((uf.u >> 16) & 1u);
    return (unsigned short)(r >> 16);
}
// float -> fp16 bits
static __device__ __forceinline__ unsigned short f2h_u(float f) {
    union { _Float16 h; unsigned short u; } c; c.h = (_Float16)f; return c.u;
}

// async global->LDS, 16B per lane. LDS dest must be wave-uniform base + lane*16.
static __device__ __forceinline__ void gload16(const void* g, void* l) {
    __builtin_amdgcn_global_load_lds(
        (const __attribute__((address_space(1))) unsigned int*)g,
        (__attribute__((address_space(3))) unsigned int*)l, 16, 0, 0);
}

// ---------------------------------------------------------------------------
// Prep: [B][C][N] f32 -> [B][N][C] fp16, both inputs in one launch.
// ---------------------------------------------------------------------------
__global__ __launch_bounds__(256) void cvt_x_k(const float* __restrict__ x,
                                               const float* __restrict__ ref_x,
                                               unsigned short* __restrict__ xtx,
                                               unsigned short* __restrict__ xtr)
{
    __shared__ unsigned short t[64][72];
    const int pt = blockIdx.x, ct = blockIdx.y;
    const int which = blockIdx.z >> 1, b = blockIdx.z & 1;
    const float* in = which ? ref_x : x;
    unsigned short* out = which ? xtr : xtx;
    const int a = threadIdx.x & 63, r = threadIdx.x >> 6;
    #pragma unroll
    for (int i = 0; i < 16; ++i) {
        int c = i * 4 + r;
        t[c][a] = f2h_u(in[((size_t)(b * C_ + ct * 64 + c) << 12) + pt * 64 + a]);
    }
    __syncthreads();
    #pragma unroll
    for (int i = 0; i < 16; ++i) {
        int p = i * 4 + r;
        out[((size_t)(b * N_ + pt * 64 + p) << 8) + ct * 64 + a] = t[a][p];
    }
}

// Prep: both weights [O][I][3][3] f32 -> [tap][O][I] fp16 in one launch
__global__ __launch_bounds__(256) void cvt_w_k(const float* __restrict__ w1,
                                               const float* __restrict__ w2,
                                               unsigned short* __restrict__ wh1,
                                               unsigned short* __restrict__ wh2)
{
    int g = blockIdx.x;
    const float* w = (g < 2304) ? w1 : w2;
    unsigned short* wh = (g < 2304) ? wh1 : wh2;
    int i = (g % 2304) * 256 + threadIdx.x;         // < 9*256*256 exactly
    int ci = i & 255, co = (i >> 8) & 255, tap = i >> 16;
    wh[i] = f2h_u(w[((size_t)(co * 256 + ci)) * 9 + tap]);
}

// ---------------------------------------------------------------------------
// Implicit-GEMM 3x3 SAME conv + bias + relu via MFMA fp16 (r4-proven version).
// All three convs fused: z = cid*2 + b. Block 256 thr = 4 waves (2co x 2pos),
// 64 cout x 128 pos tile. Weights via global_load_lds chunk-major; x-window
// reg-staged with halo + chunk swizzle. Grid 768 -> 2 blocks/CU.
// ---------------------------------------------------------------------------
__global__ __launch_bounds__(256) void conv_mfma_k(
    const unsigned short* __restrict__ xtx, const unsigned short* __restrict__ xtr,
    const unsigned short* __restrict__ w1h, const unsigned short* __restrict__ w2h,
    const float* __restrict__ b1, const float* __restrict__ b2,
    unsigned short* __restrict__ f1x, unsigned short* __restrict__ f1r,
    unsigned short* __restrict__ f2)
{
    __shared__ unsigned short As[4 * 576 * 8];   // (q*576 + tap*64 + co)*8
    __shared__ unsigned short Bs[4 * 66 * 32];   // [row][col(pad)][ci-chunk swz]
    const int tid = threadIdx.x;
    const int pt  = blockIdx.x;   // 0..31 : plane rows pt*2, pt*2+1
    const int cot = blockIdx.y;   // 0..3
    const int cid = blockIdx.z >> 1;
    const int b   = blockIdx.z & 1;

    const unsigned short* xt = (cid == 1) ? xtr : xtx;
    const unsigned short* wt = (cid == 2) ? w2h : w1h;
    const float* bias = (cid == 2) ? b2 : b1;
    unsigned short* out = (cid == 0) ? f1x : (cid == 1) ? f1r : f2;
    const int trans = (cid != 2);

    const int lane = tid & 63, wid = tid >> 6;
    const int wco = wid >> 1, wpos = wid & 1;
    const int rl = lane & 15, q = lane >> 4;
    const int r0 = pt * 2;

    f32x4 acc[2][4];
    #pragma unroll
    for (int mi = 0; mi < 2; ++mi)
        #pragma unroll
        for (int ni = 0; ni < 4; ++ni)
            #pragma unroll
            for (int e = 0; e < 4; ++e) acc[mi][ni][e] = 0.f;

    for (int k0 = 0; k0 < C_; k0 += 32) {
        // stage A via global_load_lds: wave `wid` stages k-chunk q=wid, all taps
        #pragma unroll
        for (int tap = 0; tap < 9; ++tap) {
            gload16(wt + ((size_t)(tap * C_ + cot * 64 + lane) << 8) + k0 + wid * 8,
                    &As[(wid * 576 + tap * 64 + lane) * 8]);
        }
        // stage B: 4*66*4 = 1056 16B-chunks (zero-padded halo), swizzled
        #pragma unroll
        for (int j = 0; j < 5; ++j) {
            int it = tid + j * 256;
            if (it < 1056) {
                int col = it >> 4, sub = it & 15;
                int row = sub >> 2, qb = sub & 3;
                int h = r0 + row - 1, c = col - 1;
                float4 v; v.x = 0.f; v.y = 0.f; v.z = 0.f; v.w = 0.f;
                if (h >= 0 && h < 64 && c >= 0 && c < 64)
                    v = *(const float4*)(xt + ((size_t)(b * N_ + h * 64 + c) << 8) + k0 + qb * 8);
                int chunk = qb ^ ((col >> 1) & 3);
                *(float4*)&Bs[(row * 66 + col) * 32 + chunk * 8] = v;
            }
        }
        __syncthreads();

        #pragma unroll
        for (int tap = 0; tap < 9; ++tap) {
            const int kh = tap / 3, kw = tap % 3;
            f16x8 a0 = *(const f16x8*)&As[(q * 576 + tap * 64 + wco * 32 + rl) * 8];
            f16x8 a1 = *(const f16x8*)&As[(q * 576 + tap * 64 + wco * 32 + 16 + rl) * 8];
            const int chunkB = q ^ (((rl + kw) >> 1) & 3);
            const int rowB = (wpos + kh) * 66;
            #pragma unroll
            for (int ni = 0; ni < 4; ++ni) {
                int colB = ni * 16 + rl + kw;
                f16x8 bf = *(const f16x8*)&Bs[(rowB + colB) * 32 + chunkB * 8];
                acc[0][ni] = __builtin_amdgcn_mfma_f32_16x16x32_f16(a0, bf, acc[0][ni], 0, 0, 0);
                acc[1][ni] = __builtin_amdgcn_mfma_f32_16x16x32_f16(a1, bf, acc[1][ni], 0, 0, 0);
            }
        }
        __syncthreads();
    }

    // epilogue: C/D layout col=lane&15, row=(lane>>4)*4+rr
    #pragma unroll
    for (int mi = 0; mi < 2; ++mi) {
        const int co = cot * 64 + wco * 32 + mi * 16 + q * 4;
        float bs[4];
        #pragma unroll
        for (int rr = 0; rr < 4; ++rr) bs[rr] = bias[co + rr];
        #pragma unroll
        for (int ni = 0; ni < 4; ++ni) {
            const int pos = pt * 128 + wpos * 64 + ni * 16 + rl;
            if (trans) {
                unsigned short pk[4];
                #pragma unroll
                for (int rr = 0; rr < 4; ++rr)
                    pk[rr] = f2bf(fmaxf(acc[mi][ni][rr] + bs[rr], 0.f));
                uint2 u;
                u.x = (unsigned)pk[0] | ((unsigned)pk[1] << 16);
                u.y = (unsigned)pk[2] | ((unsigned)pk[3] << 16);
                *(uint2*)&out[((size_t)(b * N_ + pos) << 8) + co] = u;
            } else {
                #pragma unroll
                for (int rr = 0; rr < 4; ++rr)
                    out[((size_t)(b * C_ + co + rr) << 12) + pos] =
                        f2bf(fmaxf(acc[mi][ni][rr] + bs[rr], 0.f));
            }
        }
    }
}

// ---------------------------------------------------------------------------
// GEMM1 (m97 structure + chunk swizzle + XCD swizzle): corrT = f1x . f1r^T
// 128x128 tile, 4 waves (2x2, each 64x64 = 4x4 frags), global_load_lds with
// pre-swizzled SOURCE chunk (dest lane-linear), swizzled read chunk.
// ---------------------------------------------------------------------------
__global__ __launch_bounds__(256) void gemm_corr_k(
    const unsigned short* __restrict__ f1x, const unsigned short* __restrict__ f1r,
    float* __restrict__ corr)
{
    __shared__ alignas(16) unsigned short As[128 * 32];
    __shared__ alignas(16) unsigned short Bs[128 * 32];
    const int tid = threadIdx.x;
    // bijective XCD swizzle over 1024 workgroups (nwg % 8 == 0)
    const int wg  = blockIdx.x + (blockIdx.y << 5);
    const int swz = (wg & 7) * 128 + (wg >> 3);
    const int tn = swz & 31, tm = swz >> 5;
    const int b  = blockIdx.z;

    const unsigned short* Ab = f1x + ((size_t)b * N_ + (size_t)tm * 128) * C_;
    const unsigned short* Bb = f1r + ((size_t)b * N_ + (size_t)tn * 128) * C_;

    const int wid = tid >> 6, lane = tid & 63;
    const int wr = wid >> 1, wc = wid & 1;
    const int rl = lane & 15, q = lane >> 4;
    const int srow = wid * 32 + (lane >> 2), sq = lane & 3;
    const int logq = sq ^ ((lane >> 3) & 3);          // pre-swizzled source chunk
    const int rswz = (rl >> 1) & 3;                   // read-side chunk xor

    f32x4 acc[4][4];
    #pragma unroll
    for (int mi = 0; mi < 4; ++mi)
        #pragma unroll
        for (int ni = 0; ni < 4; ++ni)
            #pragma unroll
            for (int e = 0; e < 4; ++e) acc[mi][ni][e] = 0.f;

    for (int k0 = 0; k0 < C_; k0 += 32) {
        gload16(&Ab[(size_t)srow * C_ + k0 + logq * 8],        &As[srow * 32 + sq * 8]);
        gload16(&Ab[(size_t)(srow + 16) * C_ + k0 + logq * 8], &As[(srow + 16) * 32 + sq * 8]);
        gload16(&Bb[(size_t)srow * C_ + k0 + logq * 8],        &Bs[srow * 32 + sq * 8]);
        gload16(&Bb[(size_t)(srow + 16) * C_ + k0 + logq * 8], &Bs[(srow + 16) * 32 + sq * 8]);
        __syncthreads();
        bf16x8 a[4], bb[4];
        #pragma unroll
        for (int mi = 0; mi < 4; ++mi)
            a[mi] = *(const bf16x8*)&As[(wr * 64 + mi * 16 + rl) * 32 + (q ^ rswz) * 8];
        #pragma unroll
        for (int ni = 0; ni < 4; ++ni)
            bb[ni] = *(const bf16x8*)&Bs[(wc * 64 + ni * 16 + rl) * 32 + (q ^ rswz) * 8];
        #pragma unroll
        for (int mi = 0; mi < 4; ++mi)
            #pragma unroll
            for (int ni = 0; ni < 4; ++ni)
                acc[mi][ni] = __builtin_amdgcn_mfma_f32_16x16x32_bf16(a[mi], bb[ni], acc[mi][ni], 0, 0, 0);
        __syncthreads();
    }

    #pragma unroll
    for (int mi = 0; mi < 4; ++mi)
        #pragma unroll
        for (int ni = 0; ni < 4; ++ni)
            #pragma unroll
            for (int rr = 0; rr < 4; ++rr) {
                int m = tm * 128 + wr * 64 + mi * 16 + q * 4 + rr;
                int n = tn * 128 + wc * 64 + ni * 16 + rl;
                corr[((size_t)b * N_ + m) * N_ + n] = acc[mi][ni][rr];
            }
}

// ---------------------------------------------------------------------------
// Row softmax over corrT rows; reads fp32, writes bf16 packed into the
// FRONT half of the same row (in-place, block owns its row).
// ---------------------------------------------------------------------------
__global__ __launch_bounds__(256) void softmax_rows_k(float* __restrict__ corr)
{
    __shared__ float red[4];
    const int m = blockIdx.x, b = blockIdx.y;
    float* row = corr + ((size_t)b * N_ + m) * N_;
    float4* row4 = (float4*)row;
    const int tid = threadIdx.x;
    const int wid = tid >> 6, lane = tid & 63;

    float4 v[4];
    float mx = -3.0e38f;
    #pragma unroll
    for (int j = 0; j < 4; ++j) {
        v[j] = row4[tid + j * 256];
        mx = fmaxf(mx, fmaxf(fmaxf(v[j].x, v[j].y), fmaxf(v[j].z, v[j].w)));
    }
    #pragma unroll
    for (int off = 32; off; off >>= 1) mx = fmaxf(mx, __shfl_xor(mx, off));
    if (lane == 0) red[wid] = mx;
    __syncthreads();
    mx = fmaxf(fmaxf(red[0], red[1]), fmaxf(red[2], red[3]));
    __syncthreads();

    float s = 0.f;
    #pragma unroll
    for (int j = 0; j < 4; ++j) {
        v[j].x = __expf(v[j].x - mx);
        v[j].y = __expf(v[j].y - mx);
        v[j].z = __expf(v[j].z - mx);
        v[j].w = __expf(v[j].w - mx);
        s += v[j].x + v[j].y + v[j].z + v[j].w;
    }
    #pragma unroll
    for (int off = 32; off; off >>= 1) s += __shfl_xor(s, off);
    if (lane == 0) red[wid] = s;
    __syncthreads();
    s = red[0] + red[1] + red[2] + red[3];
    const float inv = 1.f / s;

    unsigned short* rb = (unsigned short*)row;
    #pragma unroll
    for (int j = 0; j < 4; ++j) {
        uint2 u;
        u.x = (unsigned)f2bf(v[j].x * inv) | ((unsigned)f2bf(v[j].y * inv) << 16);
        u.y = (unsigned)f2bf(v[j].z * inv) | ((unsigned)f2bf(v[j].w * inv) << 16);
        *(uint2*)&rb[4 * (tid + j * 256)] = u;
    }
}

// ---------------------------------------------------------------------------
// GEMM2 split-K=4 + chunk swizzle + XCD swizzle: partial[s][b][c][m].
// Tile 128c x 128m, 8 waves (2c x 4m). Grid 512 blocks.
// P read as bf16 (front half of fp32 corr rows, row stride 8192 ushorts).
// Partials live in the DEAD BACK HALVES of corr rows.
// ---------------------------------------------------------------------------
__global__ __launch_bounds__(512) void gemm_out_k(
    const unsigned short* __restrict__ f2, float* __restrict__ corr)
{
    __shared__ alignas(16) unsigned short As[128 * 32];
    __shared__ alignas(16) unsigned short Bs[128 * 32];
    const int tid = threadIdx.x;
    // bijective XCD swizzle over 256 workgroups
    const int wg  = blockIdx.x + (blockIdx.y << 5);
    const int swz = (wg & 7) * 32 + (wg >> 3);
    const int tm = swz & 31;
    const int tc = (swz >> 5) >> 2;            // 0..1
    const int s  = (swz >> 5) & 3;             // split 0..3
    const int b  = blockIdx.z;

    const unsigned short* Ab = f2 + ((size_t)b * C_ + (size_t)tc * 128) * N_;
    const unsigned short* Bb = (const unsigned short*)corr
                             + ((size_t)b * N_ + (size_t)tm * 128) * 8192;

    const int wid = tid >> 6, lane = tid & 63;
    const int wc = wid >> 2, wm = wid & 3;
    const int rl = lane & 15, q = lane >> 4;
    const int srow = wid * 16 + (lane >> 2), sq = lane & 3;
    const int logq = sq ^ ((lane >> 3) & 3);
    const int rswz = (rl >> 1) & 3;
    const int nbase = s * 1024;

    f32x4 acc[4][2];
    #pragma unroll
    for (int mi = 0; mi < 4; ++mi)
        #pragma unroll
        for (int ni = 0; ni < 2; ++ni)
            #pragma unroll
            for (int e = 0; e < 4; ++e) acc[mi][ni][e] = 0.f;

    for (int kk = 0; kk < 32; ++kk) {
        const int k0 = nbase + kk * 32;
        gload16(&Ab[(size_t)srow * N_ + k0 + logq * 8],   &As[srow * 32 + sq * 8]);
        gload16(&Bb[(size_t)srow * 8192 + k0 + logq * 8], &Bs[srow * 32 + sq * 8]);
        __syncthreads();
        bf16x8 a[4], bb[2];
        #pragma unroll
        for (int mi = 0; mi < 4; ++mi)
            a[mi] = *(const bf16x8*)&As[(wc * 64 + mi * 16 + rl) * 32 + (q ^ rswz) * 8];
        #pragma unroll
        for (int ni = 0; ni < 2; ++ni)
            bb[ni] = *(const bf16x8*)&Bs[(wm * 32 + ni * 16 + rl) * 32 + (q ^ rswz) * 8];
        #pragma unroll
        for (int mi = 0; mi < 4; ++mi)
            #pragma unroll
            for (int ni = 0; ni < 2; ++ni)
                acc[mi][ni] = __builtin_amdgcn_mfma_f32_16x16x32_bf16(a[mi], bb[ni], acc[mi][ni], 0, 0, 0);
        __syncthreads();
    }

    #pragma unroll
    for (int mi = 0; mi < 4; ++mi)
        #pragma unroll
        for (int ni = 0; ni < 2; ++ni)
            #pragma unroll
            for (int rr = 0; rr < 4; ++rr) {
                int c = tc * 128 + wc * 64 + mi * 16 + q * 4 + rr;
                int m = tm * 128 + wm * 32 + ni * 16 + rl;
                size_t e = (((size_t)(s * 2 + b) * C_ + c) << 12) + m;
                corr[(e >> 11) * 4096 + 2048 + (e & 2047)] = acc[mi][ni][rr];
            }
}

// out = gamma*(p0+p1+p2+p3) + x ; partials read back from corr back-halves
__global__ __launch_bounds__(256) void reduce_k(
    const float* __restrict__ corr, const float* __restrict__ x,
    const float* __restrict__ gamma, float* __restrict__ out)
{
    const float g = gamma[0];
    size_t i = (size_t)blockIdx.x * 256 + threadIdx.x;   // float4 index
    size_t idx = i << 2;                                  // flat f32 index (b,c,m)
    float4 sum; sum.x = 0.f; sum.y = 0.f; sum.z = 0.f; sum.w = 0.f;
    #pragma unroll
    for (int sp = 0; sp < 4; ++sp) {
        size_t e = (size_t)sp * 2097152 + idx;
        float4 v = *(const float4*)&corr[(e >> 11) * 4096 + 2048 + (e & 2047)];
        sum.x += v.x; sum.y += v.y; sum.z += v.z; sum.w += v.w;
    }
    float4 xv = ((const float4*)x)[i];
    float4 o;
    o.x = sum.x * g + xv.x;
    o.y = sum.y * g + xv.y;
    o.z = sum.z * g + xv.z;
    o.w = sum.w * g + xv.w;
    ((float4*)out)[i] = o;
}

extern "C" void kernel_launch(void* const* d_in, const int* in_sizes, int n_in,
                              void* d_out, int out_size, void* d_ws, size_t ws_size,
                              hipStream_t stream) {
    const float* x     = (const float*)d_in[0];
    const float* ref_x = (const float*)d_in[1];
    const float* w1    = (const float*)d_in[2];
    const float* b1    = (const float*)d_in[3];
    const float* w2    = (const float*)d_in[4];
    const float* b2    = (const float*)d_in[5];
    const float* gamma = (const float*)d_in[6];
    float* out = (float*)d_out;

    char* ws = (char*)d_ws;
    size_t off = 0;
    auto nxt = [&](size_t bytes) {
        char* p = ws + off;
        off += (bytes + 255) & ~(size_t)255;
        return p;
    };
    unsigned short* f1x = (unsigned short*)nxt((size_t)B_ * N_ * C_ * 2);  // bf16 [b][m][c]
    unsigned short* f1r = (unsigned short*)nxt((size_t)B_ * N_ * C_ * 2);  // bf16 [b][n][c]
    unsigned short* f2  = (unsigned short*)nxt((size_t)B_ * N_ * C_ * 2);  // bf16 [b][c][n]
    unsigned short* xtx = (unsigned short*)nxt((size_t)B_ * N_ * C_ * 2);  // fp16 [b][p][c]
    unsigned short* xtr = (unsigned short*)nxt((size_t)B_ * N_ * C_ * 2);  // fp16 [b][p][c]
    unsigned short* w1h = (unsigned short*)nxt((size_t)9 * C_ * C_ * 2);   // fp16 [tap][o][i]
    unsigned short* w2h = (unsigned short*)nxt((size_t)9 * C_ * C_ * 2);   // fp16 [tap][o][i]
    float* corr = (float*)nxt((size_t)B_ * N_ * N_ * 4);                   // fp32 corrT [b][m][n]

    cvt_x_k<<<dim3(64, 4, 4), 256, 0, stream>>>(x, ref_x, xtx, xtr);
    cvt_w_k<<<4608, 256, 0, stream>>>(w1, w2, w1h, w2h);

    conv_mfma_k<<<dim3(32, 4, 6), 256, 0, stream>>>(xtx, xtr, w1h, w2h, b1, b2,
                                                    f1x, f1r, f2);

    gemm_corr_k<<<dim3(32, 32, B_), 256, 0, stream>>>(f1x, f1r, corr);
    softmax_rows_k<<<dim3(N_, B_), 256, 0, stream>>>(corr);
    gemm_out_k<<<dim3(32, 8, B_), 512, 0, stream>>>(f2, corr);
    reduce_k<<<2048, 256, 0, stream>>>(corr, x, gamma, out);
}

// Round 9
// 150.460 us; speedup vs baseline: 1.1998x; 1.1723x over previous
//
#include <hip/hip_runtime.h>
#include <hip/hip_bf16.h>

#define B_ 2
#define C_ 256
#define H_ 64
#define W_ 64
#define N_ 4096  // H_*W_

typedef short bf16x8 __attribute__((ext_vector_type(8)));
typedef _Float16 f16x8 __attribute__((ext_vector_type(8)));
typedef float f32x4 __attribute__((ext_vector_type(4)));
typedef float f32x16 __attribute__((ext_vector_type(16)));

// float -> bf16 (round to nearest even), finite inputs
static __device__ __forceinline__ unsigned short f2bf(float f) {
    union { float f; unsigned u; } uf; uf.f = f;
    unsigned r = uf.u + 0x7fffu + ((uf.u >> 16) & 1u);
    return (unsigned short)(r >> 16);
}
// float -> fp16 bits
static __device__ __forceinline__ unsigned short f2h_u(float f) {
    union { _Float16 h; unsigned short u; } c; c.h = (_Float16)f; return c.u;
}

// async global->LDS, 16B per lane. LDS dest must be wave-uniform base + lane*16.
static __device__ __forceinline__ void gload16(const void* g, void* l) {
    __builtin_amdgcn_global_load_lds(
        (const __attribute__((address_space(1))) unsigned int*)g,
        (__attribute__((address_space(3))) unsigned int*)l, 16, 0, 0);
}

// ---------------------------------------------------------------------------
// Prep: [B][C][N] f32 -> [B][N][C] fp16, both inputs in one launch.
// ---------------------------------------------------------------------------
__global__ __launch_bounds__(256) void cvt_x_k(const float* __restrict__ x,
                                               const float* __restrict__ ref_x,
                                               unsigned short* __restrict__ xtx,
                                               unsigned short* __restrict__ xtr)
{
    __shared__ unsigned short t[64][72];
    const int pt = blockIdx.x, ct = blockIdx.y;
    const int which = blockIdx.z >> 1, b = blockIdx.z & 1;
    const float* in = which ? ref_x : x;
    unsigned short* out = which ? xtr : xtx;
    const int a = threadIdx.x & 63, r = threadIdx.x >> 6;
    #pragma unroll
    for (int i = 0; i < 16; ++i) {
        int c = i * 4 + r;
        t[c][a] = f2h_u(in[((size_t)(b * C_ + ct * 64 + c) << 12) + pt * 64 + a]);
    }
    __syncthreads();
    #pragma unroll
    for (int i = 0; i < 16; ++i) {
        int p = i * 4 + r;
        out[((size_t)(b * N_ + pt * 64 + p) << 8) + ct * 64 + a] = t[a][p];
    }
}

// Prep: both weights [O][I][3][3] f32 -> [tap][O][I] fp16 in one launch
__global__ __launch_bounds__(256) void cvt_w_k(const float* __restrict__ w1,
                                               const float* __restrict__ w2,
                                               unsigned short* __restrict__ wh1,
                                               unsigned short* __restrict__ wh2)
{
    int g = blockIdx.x;
    const float* w = (g < 2304) ? w1 : w2;
    unsigned short* wh = (g < 2304) ? wh1 : wh2;
    int i = (g % 2304) * 256 + threadIdx.x;         // < 9*256*256 exactly
    int ci = i & 255, co = (i >> 8) & 255, tap = i >> 16;
    wh[i] = f2h_u(w[((size_t)(co * 256 + ci)) * 9 + tap]);
}

// ---------------------------------------------------------------------------
// Implicit-GEMM 3x3 SAME conv + bias + relu via MFMA fp16 (r4-proven version).
// ---------------------------------------------------------------------------
__global__ __launch_bounds__(256) void conv_mfma_k(
    const unsigned short* __restrict__ xtx, const unsigned short* __restrict__ xtr,
    const unsigned short* __restrict__ w1h, const unsigned short* __restrict__ w2h,
    const float* __restrict__ b1, const float* __restrict__ b2,
    unsigned short* __restrict__ f1x, unsigned short* __restrict__ f1r,
    unsigned short* __restrict__ f2)
{
    __shared__ unsigned short As[4 * 576 * 8];   // (q*576 + tap*64 + co)*8
    __shared__ unsigned short Bs[4 * 66 * 32];   // [row][col(pad)][ci-chunk swz]
    const int tid = threadIdx.x;
    const int pt  = blockIdx.x;   // 0..31 : plane rows pt*2, pt*2+1
    const int cot = blockIdx.y;   // 0..3
    const int cid = blockIdx.z >> 1;
    const int b   = blockIdx.z & 1;

    const unsigned short* xt = (cid == 1) ? xtr : xtx;
    const unsigned short* wt = (cid == 2) ? w2h : w1h;
    const float* bias = (cid == 2) ? b2 : b1;
    unsigned short* out = (cid == 0) ? f1x : (cid == 1) ? f1r : f2;
    const int trans = (cid != 2);

    const int lane = tid & 63, wid = tid >> 6;
    const int wco = wid >> 1, wpos = wid & 1;
    const int rl = lane & 15, q = lane >> 4;
    const int r0 = pt * 2;

    f32x4 acc[2][4];
    #pragma unroll
    for (int mi = 0; mi < 2; ++mi)
        #pragma unroll
        for (int ni = 0; ni < 4; ++ni)
            #pragma unroll
            for (int e = 0; e < 4; ++e) acc[mi][ni][e] = 0.f;

    for (int k0 = 0; k0 < C_; k0 += 32) {
        #pragma unroll
        for (int tap = 0; tap < 9; ++tap) {
            gload16(wt + ((size_t)(tap * C_ + cot * 64 + lane) << 8) + k0 + wid * 8,
                    &As[(wid * 576 + tap * 64 + lane) * 8]);
        }
        #pragma unroll
        for (int j = 0; j < 5; ++j) {
            int it = tid + j * 256;
            if (it < 1056) {
                int col = it >> 4, sub = it & 15;
                int row = sub >> 2, qb = sub & 3;
                int h = r0 + row - 1, c = col - 1;
                float4 v; v.x = 0.f; v.y = 0.f; v.z = 0.f; v.w = 0.f;
                if (h >= 0 && h < 64 && c >= 0 && c < 64)
                    v = *(const float4*)(xt + ((size_t)(b * N_ + h * 64 + c) << 8) + k0 + qb * 8);
                int chunk = qb ^ ((col >> 1) & 3);
                *(float4*)&Bs[(row * 66 + col) * 32 + chunk * 8] = v;
            }
        }
        __syncthreads();

        #pragma unroll
        for (int tap = 0; tap < 9; ++tap) {
            const int kh = tap / 3, kw = tap % 3;
            f16x8 a0 = *(const f16x8*)&As[(q * 576 + tap * 64 + wco * 32 + rl) * 8];
            f16x8 a1 = *(const f16x8*)&As[(q * 576 + tap * 64 + wco * 32 + 16 + rl) * 8];
            const int chunkB = q ^ (((rl + kw) >> 1) & 3);
            const int rowB = (wpos + kh) * 66;
            #pragma unroll
            for (int ni = 0; ni < 4; ++ni) {
                int colB = ni * 16 + rl + kw;
                f16x8 bf = *(const f16x8*)&Bs[(rowB + colB) * 32 + chunkB * 8];
                acc[0][ni] = __builtin_amdgcn_mfma_f32_16x16x32_f16(a0, bf, acc[0][ni], 0, 0, 0);
                acc[1][ni] = __builtin_amdgcn_mfma_f32_16x16x32_f16(a1, bf, acc[1][ni], 0, 0, 0);
            }
        }
        __syncthreads();
    }

    #pragma unroll
    for (int mi = 0; mi < 2; ++mi) {
        const int co = cot * 64 + wco * 32 + mi * 16 + q * 4;
        float bs[4];
        #pragma unroll
        for (int rr = 0; rr < 4; ++rr) bs[rr] = bias[co + rr];
        #pragma unroll
        for (int ni = 0; ni < 4; ++ni) {
            const int pos = pt * 128 + wpos * 64 + ni * 16 + rl;
            if (trans) {
                unsigned short pk[4];
                #pragma unroll
                for (int rr = 0; rr < 4; ++rr)
                    pk[rr] = f2bf(fmaxf(acc[mi][ni][rr] + bs[rr], 0.f));
                uint2 u;
                u.x = (unsigned)pk[0] | ((unsigned)pk[1] << 16);
                u.y = (unsigned)pk[2] | ((unsigned)pk[3] << 16);
                *(uint2*)&out[((size_t)(b * N_ + pos) << 8) + co] = u;
            } else {
                #pragma unroll
                for (int rr = 0; rr < 4; ++rr)
                    out[((size_t)(b * C_ + co + rr) << 12) + pos] =
                        f2bf(fmaxf(acc[mi][ni][rr] + bs[rr], 0.f));
            }
        }
    }
}

// ---------------------------------------------------------------------------
// Flash attention: out_part[se][b][c][m] = sum_{n in split} exp(S[n][m]-m_run)*V[n][c]
// S[n][m] = sum_ch K[n][ch]*Q[m][ch]  (swapped-operand QK^T: m = lane-col)
// Block: m-tile 32, 4 waves: wn = wid&1 splits n (n32 each of a 64-n stage),
// wc2 = wid>>1 splits c (128 each). Grid (128 m-tiles, s=2, b=2) = 512 blocks.
// Splits se = s*2+wn: 4 unnormalized partials + (m_run,l) stats; combine_k sums.
// 32x32x16 bf16 frags (layouts verified r5/r6). P-build: pack + shfl_xor(32).
// ---------------------------------------------------------------------------
__global__ __launch_bounds__(256, 2) void flash_k(
    const unsigned short* __restrict__ f1x,  // Q  [b][m][ch] bf16
    const unsigned short* __restrict__ f1r,  // K  [b][n][ch] bf16
    const unsigned short* __restrict__ f2,   // V^T [b][c][n] bf16
    float* __restrict__ part,                // [4][B][C][N] f32
    float* __restrict__ stats)               // float2 [4][B][N]
{
    __shared__ unsigned short Ks[64 * 264];  // [n64][256ch + 8 pad]
    __shared__ unsigned short Vs[256 * 72];  // [c256][64n + 8 pad]
    const int tid = threadIdx.x;
    const int mt = blockIdx.x, s = blockIdx.y, b = blockIdx.z;
    const int m0 = mt * 32;
    const int lane = tid & 63, wid = tid >> 6;
    const int wn = wid & 1, wc2 = wid >> 1;
    const int rl = lane & 31, l5 = lane >> 5;
    const int c0w = wc2 * 128;
    const int nw = wn * 32;

    // Q B-frags for 16 ch-steps (row m = rl, k = l5*8+j)
    bf16x8 Qf[16];
    #pragma unroll
    for (int st = 0; st < 16; ++st)
        Qf[st] = *(const bf16x8*)&f1x[(((size_t)b * N_ + m0 + rl) << 8) + st * 16 + l5 * 8];

    f32x16 O[4];
    #pragma unroll
    for (int cf = 0; cf < 4; ++cf)
        #pragma unroll
        for (int e = 0; e < 16; ++e) O[cf][e] = 0.f;
    float m_run = -1e30f, l_run = 0.f;

    const int nbase = s * 2048;
    for (int r = 0; r < 32; ++r) {
        const int n0 = nbase + r * 64;
        // stage K: 64 rows x 32 chunks = 2048
        #pragma unroll
        for (int j = 0; j < 8; ++j) {
            int it = tid + j * 256;
            int n = it >> 5, cq = it & 31;
            *(float4*)&Ks[n * 264 + cq * 8] =
                *(const float4*)&f1r[(((size_t)b * N_ + n0 + n) << 8) + cq * 8];
        }
        // stage V: 256 rows x 8 chunks = 2048
        #pragma unroll
        for (int j = 0; j < 8; ++j) {
            int it = tid + j * 256;
            int c = it >> 3, nq = it & 7;
            *(float4*)&Vs[c * 72 + nq * 8] =
                *(const float4*)&f2[(((size_t)b * C_ + c) << 12) + n0 + nq * 8];
        }
        __syncthreads();

        // QK^T (swapped): S rows = n (reg pattern), col = m = rl
        f32x16 S;
        #pragma unroll
        for (int e = 0; e < 16; ++e) S[e] = 0.f;
        #pragma unroll
        for (int st = 0; st < 16; ++st) {
            bf16x8 Kf = *(const bf16x8*)&Ks[(nw + rl) * 264 + st * 16 + l5 * 8];
            S = __builtin_amdgcn_mfma_f32_32x32x16_bf16(Kf, Qf[st], S, 0, 0, 0);
        }

        // online softmax for m = rl over this wave's 32 n
        float mx = S[0];
        #pragma unroll
        for (int e = 1; e < 16; ++e) mx = fmaxf(mx, S[e]);
        mx = fmaxf(mx, __shfl_xor(mx, 32));
        float m_new = fmaxf(m_run, mx);
        float sc = __expf(m_run - m_new);
        float p[16]; float lsum = 0.f;
        #pragma unroll
        for (int e = 0; e < 16; ++e) { p[e] = __expf(S[e] - m_new); lsum += p[e]; }
        l_run = l_run * sc + lsum;
        m_run = m_new;
        #pragma unroll
        for (int cf = 0; cf < 4; ++cf)
            #pragma unroll
            for (int e = 0; e < 16; ++e) O[cf][e] *= sc;

        // P -> bf16 B-frags (row m = rl, k = n-local). n(reg r) = (r&3)+8*(r>>2)+4*l5
        unsigned pk_[8], xk[8];
        #pragma unroll
        for (int g = 0; g < 8; ++g)
            pk_[g] = (unsigned)f2bf(p[2 * g]) | ((unsigned)f2bf(p[2 * g + 1]) << 16);
        #pragma unroll
        for (int g = 0; g < 8; ++g) xk[g] = (unsigned)__shfl_xor((int)pk_[g], 32);
        union { unsigned d[4]; bf16x8 v; } P0, P1;
        P0.d[0] = l5 ? xk[2] : pk_[0];
        P0.d[1] = l5 ? xk[3] : pk_[1];
        P0.d[2] = l5 ? pk_[2] : xk[0];
        P0.d[3] = l5 ? pk_[3] : xk[1];
        P1.d[0] = l5 ? xk[6] : pk_[4];
        P1.d[1] = l5 ? xk[7] : pk_[5];
        P1.d[2] = l5 ? pk_[6] : xk[4];
        P1.d[3] = l5 ? pk_[7] : xk[5];

        // PV: A = V^T rows c, B = P rows m -> O rows c, col m
        #pragma unroll
        for (int cf = 0; cf < 4; ++cf) {
            const int vrow = (c0w + cf * 32 + rl) * 72;
            bf16x8 Vf0 = *(const bf16x8*)&Vs[vrow + nw + l5 * 8];
            O[cf] = __builtin_amdgcn_mfma_f32_32x32x16_bf16(Vf0, P0.v, O[cf], 0, 0, 0);
            bf16x8 Vf1 = *(const bf16x8*)&Vs[vrow + nw + 16 + l5 * 8];
            O[cf] = __builtin_amdgcn_mfma_f32_32x32x16_bf16(Vf1, P1.v, O[cf], 0, 0, 0);
        }
        __syncthreads();
    }

    // epilogue: unnormalized partial + stats
    float l_tot = l_run + __shfl_xor(l_run, 32);
    const int se = s * 2 + wn;
    float* pb = part + (size_t)se * ((size_t)B_ * C_ * N_);
    #pragma unroll
    for (int cf = 0; cf < 4; ++cf)
        #pragma unroll
        for (int e = 0; e < 16; ++e) {
            int c = c0w + cf * 32 + (e & 3) + 8 * (e >> 2) + 4 * l5;
            pb[(((size_t)b * C_ + c) << 12) + m0 + rl] = O[cf][e];
        }
    if (wc2 == 0 && l5 == 0) {
        float2 st; st.x = m_run; st.y = l_tot;
        ((float2*)stats)[(((size_t)(se * 2 + b)) << 12) + m0 + rl] = st;
    }
}

// ---------------------------------------------------------------------------
// Combine: out[b][c][m] = gamma * (sum_se w_se*part_se) / (sum_se w_se*l_se) + x
// w_se = exp(m_se - max_se m_se). Elementwise over [b][c][m], float4.
// ---------------------------------------------------------------------------
__global__ __launch_bounds__(256) void combine_k(
    const float* __restrict__ part, const float* __restrict__ stats,
    const float* __restrict__ x, const float* __restrict__ gamma,
    float* __restrict__ out)
{
    const float g = gamma[0];
    size_t i = (size_t)blockIdx.x * 256 + threadIdx.x;
    size_t idx = i << 2;
    const int m = (int)(idx & 4095);
    const int b = (int)(idx >> 20);              // /(C*N)=2^20
    const size_t PS = (size_t)B_ * C_ * N_;

    float ms[4][4], ls[4][4];
    #pragma unroll
    for (int se = 0; se < 4; ++se) {
        const float2* sp = (const float2*)stats + (((size_t)(se * 2 + b)) << 12) + m;
        #pragma unroll
        for (int j = 0; j < 4; ++j) { float2 v = sp[j]; ms[se][j] = v.x; ls[se][j] = v.y; }
    }
    float w[4][4], den[4] = {0.f, 0.f, 0.f, 0.f};
    #pragma unroll
    for (int j = 0; j < 4; ++j) {
        float M = fmaxf(fmaxf(ms[0][j], ms[1][j]), fmaxf(ms[2][j], ms[3][j]));
        #pragma unroll
        for (int se = 0; se < 4; ++se) {
            w[se][j] = __expf(ms[se][j] - M);
            den[j] += w[se][j] * ls[se][j];
        }
    }
    float num[4] = {0.f, 0.f, 0.f, 0.f};
    #pragma unroll
    for (int se = 0; se < 4; ++se) {
        float4 p = *(const float4*)&part[se * PS + idx];
        num[0] += w[se][0] * p.x; num[1] += w[se][1] * p.y;
        num[2] += w[se][2] * p.z; num[3] += w[se][3] * p.w;
    }
    float4 xv = ((const float4*)x)[i];
    float4 o;
    o.x = g * num[0] / den[0] + xv.x;
    o.y = g * num[1] / den[1] + xv.y;
    o.z = g * num[2] / den[2] + xv.z;
    o.w = g * num[3] / den[3] + xv.w;
    ((float4*)out)[i] = o;
}

extern "C" void kernel_launch(void* const* d_in, const int* in_sizes, int n_in,
                              void* d_out, int out_size, void* d_ws, size_t ws_size,
                              hipStream_t stream) {
    const float* x     = (const float*)d_in[0];
    const float* ref_x = (const float*)d_in[1];
    const float* w1    = (const float*)d_in[2];
    const float* b1    = (const float*)d_in[3];
    const float* w2    = (const float*)d_in[4];
    const float* b2    = (const float*)d_in[5];
    const float* gamma = (const float*)d_in[6];
    float* out = (float*)d_out;

    char* ws = (char*)d_ws;
    size_t off = 0;
    auto nxt = [&](size_t bytes) {
        char* p = ws + off;
        off += (bytes + 255) & ~(size_t)255;
        return p;
    };
    unsigned short* f1x = (unsigned short*)nxt((size_t)B_ * N_ * C_ * 2);  // bf16 [b][m][c]
    unsigned short* f1r = (unsigned short*)nxt((size_t)B_ * N_ * C_ * 2);  // bf16 [b][n][c]
    unsigned short* f2  = (unsigned short*)nxt((size_t)B_ * N_ * C_ * 2);  // bf16 [b][c][n]
    unsigned short* xtx = (unsigned short*)nxt((size_t)B_ * N_ * C_ * 2);  // fp16 [b][p][c]
    unsigned short* xtr = (unsigned short*)nxt((size_t)B_ * N_ * C_ * 2);  // fp16 [b][p][c]
    unsigned short* w1h = (unsigned short*)nxt((size_t)9 * C_ * C_ * 2);   // fp16 [tap][o][i]
    unsigned short* w2h = (unsigned short*)nxt((size_t)9 * C_ * C_ * 2);   // fp16 [tap][o][i]
    float* part  = (float*)nxt((size_t)4 * B_ * C_ * N_ * 4);              // 33.5 MB
    float* stats = (float*)nxt((size_t)4 * B_ * N_ * 8);                   // float2

    cvt_x_k<<<dim3(64, 4, 4), 256, 0, stream>>>(x, ref_x, xtx, xtr);
    cvt_w_k<<<4608, 256, 0, stream>>>(w1, w2, w1h, w2h);

    conv_mfma_k<<<dim3(32, 4, 6), 256, 0, stream>>>(xtx, xtr, w1h, w2h, b1, b2,
                                                    f1x, f1r, f2);

    flash_k<<<dim3(128, 2, 2), 256, 0, stream>>>(f1x, f1r, f2, part, stats);
    combine_k<<<2048, 256, 0, stream>>>(part, stats, x, gamma, out);
}